// Round 4
// baseline (389.125 us; speedup 1.0000x reference)
//
#include <hip/hip_runtime.h>
#include <hip/hip_cooperative_groups.h>
namespace cg = cooperative_groups;

#define FD 128
#define CHUNK 12800           // nodes per LDS chunk (51.2 KB)
#define NCHUNK 8              // covers n <= 102400
#define NSLICE 56             // edge slices
#define MGRID (NCHUNK * NSLICE)   // 448 blocks (<= 2/CU * 256 CU)
#define MBLK 512
#define QSCALE 16777216.0f    // 2^24
#define QINV   5.9604644775390625e-8f

__device__ __forceinline__ unsigned quant_w(int dp1) {
    return (unsigned)(rsqrtf((float)dp1) * QSCALE + 0.5f);
}

// Block-uniform dtype check: OR of first kmax odd u32 words.
// int64 buffer => high halves all zero; int32 => random node ids, nonzero w.h.p.
__device__ __forceinline__ bool detect_is32(const unsigned int* w, unsigned int* sflag,
                                            int tid, int nthr, int kmax) {
    if (tid == 0) *sflag = 0u;
    __syncthreads();
    unsigned acc = 0;
    for (int k = tid; k < kmax; k += nthr) acc |= w[2 * k + 1];
    if (acc) atomicOr(sflag, 1u);
    __syncthreads();
    return *sflag != 0u;
}

// int64 -> int32 (no-op when already int32; every block self-detects on a common region)
__global__ void convert_kernel(const unsigned int* __restrict__ w64,
                               int* __restrict__ e32, long long total) {
    __shared__ unsigned int sflag;
    int kmax = (int)((total / 2 < 256) ? total / 2 : 256);
    bool is32 = detect_is32(w64, &sflag, threadIdx.x, blockDim.x, kmax);
    if (is32) return;
    const long long* e64 = (const long long*)w64;
    const long long R = ((total + gridDim.x - 1) / gridDim.x + 1) & ~1LL;
    const long long base = (long long)blockIdx.x * R;
    long long end = base + R; if (end > total) end = total;
    for (long long i = base + (long long)threadIdx.x * 2; i + 1 < end;
         i += (long long)blockDim.x * 2) {
        longlong2 v = *reinterpret_cast<const longlong2*>(e64 + i);
        *reinterpret_cast<int2*>(e32 + i) = make_int2((int)v.x, (int)v.y);
    }
}

__global__ __launch_bounds__(MBLK, 4) void mega_kernel(
        const float* __restrict__ x, const float* __restrict__ Wm,
        const float* __restrict__ bias, const void* __restrict__ ei,
        const int* __restrict__ e32,
        int* __restrict__ deg, float* __restrict__ coef,
        unsigned int* __restrict__ psD, unsigned int* __restrict__ psS,
        float* __restrict__ P, float* __restrict__ t,
        float* __restrict__ out, long long n, long long E) {
    cg::grid_group grid = cg::this_grid();
    __shared__ unsigned int hist[CHUNK];
    __shared__ unsigned int sflag;

    const int tid = threadIdx.x;
    const int b = blockIdx.x;
    const int c = b & (NCHUNK - 1);
    const int j = b >> 3;                      // log2(NCHUNK)
    const bool is32 = detect_is32((const unsigned int*)ei, &sflag, tid, MBLK, 256);
    const int* SRC = is32 ? (const int*)ei : e32;
    const int* DST = SRC + E;
    const long long SL = ((E + NSLICE - 1) / NSLICE + 3) & ~3LL;
    const long long e0 = (long long)j * SL;
    long long e1 = e0 + SL; if (e1 > E) e1 = E; if (e1 < e0) e1 = e0;
    const long long e1v = e0 + ((e1 - e0) & ~3LL);
    const int lo = c * CHUNK;
    const long long gtid = (long long)b * MBLK + tid;

    // ---- phase 1: degree histogram over dst ----
    for (int i = tid; i < CHUNK; i += MBLK) hist[i] = 0u;
    __syncthreads();
    for (long long i = e0 + (long long)tid * 4; i < e1v; i += (long long)MBLK * 4) {
        int4 d = *reinterpret_cast<const int4*>(DST + i);
        unsigned u0 = (unsigned)(d.x - lo), u1 = (unsigned)(d.y - lo);
        unsigned u2 = (unsigned)(d.z - lo), u3 = (unsigned)(d.w - lo);
        if (u0 < CHUNK) atomicAdd(&hist[u0], 1u);
        if (u1 < CHUNK) atomicAdd(&hist[u1], 1u);
        if (u2 < CHUNK) atomicAdd(&hist[u2], 1u);
        if (u3 < CHUNK) atomicAdd(&hist[u3], 1u);
    }
    { long long it = e1v + tid;
      if (it < e1) { unsigned u = (unsigned)(DST[it] - lo); if (u < CHUNK) atomicAdd(&hist[u], 1u); } }
    __syncthreads();
    { unsigned int* o = psD + (size_t)b * (CHUNK / 2);
      for (int w = tid; w < CHUNK / 2; w += MBLK)
          o[w] = (hist[2 * w] & 0xffffu) | (hist[2 * w + 1] << 16); }
    grid.sync();

    // ---- phase 2: reduce degree partials ----
    { const long long NW = (long long)NCHUNK * (CHUNK / 2);
      if (gtid < NW) {
          int cc = (int)(gtid / (CHUNK / 2));
          int w  = (int)(gtid % (CHUNK / 2));
          unsigned s0 = 0, s1 = 0;
          for (int jj = 0; jj < NSLICE; ++jj) {
              unsigned v = psD[((size_t)jj * NCHUNK + cc) * (CHUNK / 2) + w];
              s0 += v & 0xffffu; s1 += v >> 16;
          }
          long long v0 = (long long)cc * CHUNK + 2 * w;
          if (v0 < n) deg[v0] = (int)s0;
          if (v0 + 1 < n) deg[v0 + 1] = (int)s1;
      } }
    grid.sync();

    // ---- phase 3: weighted src histogram (deg gather + quant folded in) ----
    for (int i = tid; i < CHUNK; i += MBLK) hist[i] = 0u;
    __syncthreads();
    for (long long i = e0 + (long long)tid * 4; i < e1v; i += (long long)MBLK * 4) {
        int4 s = *reinterpret_cast<const int4*>(SRC + i);
        int4 d = *reinterpret_cast<const int4*>(DST + i);
        unsigned u0 = (unsigned)(s.x - lo), u1 = (unsigned)(s.y - lo);
        unsigned u2 = (unsigned)(s.z - lo), u3 = (unsigned)(s.w - lo);
        if (u0 < CHUNK) atomicAdd(&hist[u0], quant_w(deg[d.x] + 1));
        if (u1 < CHUNK) atomicAdd(&hist[u1], quant_w(deg[d.y] + 1));
        if (u2 < CHUNK) atomicAdd(&hist[u2], quant_w(deg[d.z] + 1));
        if (u3 < CHUNK) atomicAdd(&hist[u3], quant_w(deg[d.w] + 1));
    }
    { long long it = e1v + tid;
      if (it < e1) { unsigned u = (unsigned)(SRC[it] - lo);
                     if (u < CHUNK) atomicAdd(&hist[u], quant_w(deg[DST[it]] + 1)); } }
    __syncthreads();
    { unsigned int* o = psS + (size_t)b * CHUNK;
      for (int w = tid; w < CHUNK; w += MBLK) o[w] = hist[w]; }
    grid.sync();

    // ---- phase 4: reduce S partials -> coef ----
    if (gtid < n) {
        int cc = (int)(gtid / CHUNK);
        int u  = (int)(gtid % CHUNK);
        unsigned s = 0;
        for (int jj = 0; jj < NSLICE; ++jj)
            s += psS[((size_t)jj * NCHUNK + cc) * CHUNK + u];
        float dg = (float)(deg[gtid] + 1);
        float di = rsqrtf(dg);
        coef[gtid] = di * ((float)s * QINV) + 1.0f / dg;
    }
    grid.sync();

    // ---- phase 5: t-partials (deterministic tree reduce, no float atomics) ----
    {
        float4 a = make_float4(0.f, 0.f, 0.f, 0.f);
        const long long tot = n * (FD / 4);
        for (long long i = gtid; i < tot; i += (long long)MGRID * MBLK) {
            float cf = coef[i >> 5];
            float4 xv = reinterpret_cast<const float4*>(x)[i];
            a.x += cf * xv.x; a.y += cf * xv.y; a.z += cf * xv.z; a.w += cf * xv.w;
        }
        float4* sm4 = reinterpret_cast<float4*>(hist);   // 8 KB of the 51.2 KB
        const int lane = tid & 31, grp = tid >> 5;
        sm4[grp * 32 + lane] = a;
        __syncthreads();
        for (int s2 = 8; s2 > 0; s2 >>= 1) {
            if (grp < s2) {
                float4 o = sm4[(grp + s2) * 32 + lane];
                float4 m = sm4[grp * 32 + lane];
                m.x += o.x; m.y += o.y; m.z += o.z; m.w += o.w;
                sm4[grp * 32 + lane] = m;
            }
            __syncthreads();
        }
        if (tid < 32) reinterpret_cast<float4*>(P)[b * 32 + tid] = sm4[tid];
    }
    grid.sync();

    // ---- phase 6: column-sum partials -> t ----
    if (b < FD) {
        float* smf = reinterpret_cast<float*>(hist);
        smf[tid] = (tid < MGRID) ? P[(size_t)tid * FD + b] : 0.f;
        __syncthreads();
        for (int s2 = MBLK / 2; s2 > 0; s2 >>= 1) {
            if (tid < s2) smf[tid] += smf[tid + s2];
            __syncthreads();
        }
        if (tid == 0) t[b] = smf[0];
    }
    grid.sync();

    // ---- phase 7: out = W t + n*bias ----
    if (b == 0) {
        float* smf = reinterpret_cast<float*>(hist);
        if (tid < FD) smf[tid] = t[tid];
        __syncthreads();
        if (tid < FD) {
            float a0 = 0.f;
            #pragma unroll 16
            for (int k = 0; k < FD; ++k) a0 += Wm[tid * FD + k] * smf[k];
            out[tid] = a0 + (float)n * bias[tid];
        }
    }
}

// ================= fallback (R2-proven global-atomic path) =================
__global__ void deg_fb(const void* __restrict__ ei, int* __restrict__ deg, long long E) {
    __shared__ unsigned int sflag;
    int kmax = (int)((E < 256) ? (E > 0 ? E - 1 : 0) : 256);
    bool is32 = detect_is32((const unsigned int*)ei, &sflag, threadIdx.x, blockDim.x, kmax);
    const long long st = (long long)gridDim.x * blockDim.x;
    long long i = blockIdx.x * (long long)blockDim.x + threadIdx.x;
    if (is32) { const int* D = (const int*)ei + E;
        for (; i < E; i += st) atomicAdd(&deg[D[i]], 1);
    } else { const long long* D = (const long long*)ei + E;
        for (; i < E; i += st) atomicAdd(&deg[(int)D[i]], 1);
    }
}

__global__ void srcsum_fb(const void* __restrict__ ei, const int* __restrict__ deg,
                          unsigned int* __restrict__ Sq, long long E) {
    __shared__ unsigned int sflag;
    int kmax = (int)((E < 256) ? (E > 0 ? E - 1 : 0) : 256);
    bool is32 = detect_is32((const unsigned int*)ei, &sflag, threadIdx.x, blockDim.x, kmax);
    const long long st = (long long)gridDim.x * blockDim.x;
    long long i = blockIdx.x * (long long)blockDim.x + threadIdx.x;
    if (is32) { const int* S = (const int*)ei; const int* D = S + E;
        for (; i < E; i += st) atomicAdd(&Sq[S[i]], quant_w(deg[D[i]] + 1));
    } else { const long long* S = (const long long*)ei; const long long* D = S + E;
        for (; i < E; i += st) atomicAdd(&Sq[(int)S[i]], quant_w(deg[(int)D[i]] + 1));
    }
}

__global__ void coef_fb(unsigned int* __restrict__ Sq, const int* __restrict__ deg,
                        long long n) {
    const long long v = blockIdx.x * (long long)blockDim.x + threadIdx.x;
    if (v >= n) return;
    unsigned s = Sq[v];
    float dg = (float)(deg[v] + 1);
    float di = rsqrtf(dg);
    ((float*)Sq)[v] = di * ((float)s * QINV) + 1.0f / dg;   // in-place, own slot
}

__global__ void redx_fb(const float* __restrict__ x, const float* __restrict__ coef,
                        float* __restrict__ t, long long n) {
    __shared__ float sm[FD];
    for (int f = threadIdx.x; f < FD; f += blockDim.x) sm[f] = 0.f;
    __syncthreads();
    const long long tot = n * (FD / 4);
    const long long st = (long long)gridDim.x * blockDim.x;
    const int lane = threadIdx.x & 31;
    float4 a = make_float4(0.f, 0.f, 0.f, 0.f);
    for (long long i = blockIdx.x * (long long)blockDim.x + threadIdx.x; i < tot; i += st) {
        float cf = coef[i >> 5];
        float4 xv = reinterpret_cast<const float4*>(x)[i];
        a.x += cf * xv.x; a.y += cf * xv.y; a.z += cf * xv.z; a.w += cf * xv.w;
    }
    atomicAdd(&sm[lane * 4 + 0], a.x);
    atomicAdd(&sm[lane * 4 + 1], a.y);
    atomicAdd(&sm[lane * 4 + 2], a.z);
    atomicAdd(&sm[lane * 4 + 3], a.w);
    __syncthreads();
    for (int f = threadIdx.x; f < FD; f += blockDim.x) atomicAdd(&t[f], sm[f]);
}

__global__ void final_fb(const float* __restrict__ Wm, const float* __restrict__ bias,
                         const float* __restrict__ t, float* __restrict__ out, float nn) {
    __shared__ float ts[FD];
    int f = threadIdx.x;
    if (f < FD) ts[f] = t[f];
    __syncthreads();
    if (f < FD) {
        float a0 = 0.f;
        #pragma unroll 16
        for (int k = 0; k < FD; ++k) a0 += Wm[f * FD + k] * ts[k];
        out[f] = a0 + nn * bias[f];
    }
}

// ==============================================================================
extern "C" void kernel_launch(void* const* d_in, const int* in_sizes, int n_in,
                              void* d_out, int out_size, void* d_ws, size_t ws_size,
                              hipStream_t stream) {
    const float* x    = (const float*)d_in[0];
    const float* W    = (const float*)d_in[1];
    const float* bias = (const float*)d_in[2];
    const void*  ei   = d_in[3];
    float* out = (float*)d_out;
    long long n = in_sizes[0] / FD;                  // 100000
    long long E = (long long)in_sizes[3] / 2;        // 1600000

    char* ws = (char*)d_ws;
    size_t off = 0;
    auto take = [&](size_t bytes) { size_t r = off; off += (bytes + 255) & ~(size_t)255; return r; };
    int*          e32  = (int*)(ws + take((size_t)2 * E * 4));
    unsigned int* psD  = (unsigned int*)(ws + take((size_t)MGRID * (CHUNK / 2) * 4));
    unsigned int* psS  = (unsigned int*)(ws + take((size_t)MGRID * CHUNK * 4));
    int*          deg  = (int*)(ws + take((size_t)NCHUNK * CHUNK * 4));
    float*        coef = (float*)(ws + take((size_t)NCHUNK * CHUNK * 4));
    float*        P    = (float*)(ws + take((size_t)MGRID * FD * 4));
    float*        t    = (float*)(ws + take((size_t)FD * 4));
    const size_t need = off;

    const bool main_ok = (n <= (long long)NCHUNK * CHUNK) && ((E & 3) == 0) &&
                         (E >= 512) && (ws_size >= need);

    if (main_ok) {
        convert_kernel<<<512, 256, 0, stream>>>((const unsigned int*)ei, e32, 2 * E);
        void* args[] = { (void*)&x, (void*)&W, (void*)&bias, (void*)&ei, (void*)&e32,
                         (void*)&deg, (void*)&coef, (void*)&psD, (void*)&psS,
                         (void*)&P, (void*)&t, (void*)&out, (void*)&n, (void*)&E };
        hipLaunchCooperativeKernel((void*)mega_kernel, dim3(MGRID), dim3(MBLK),
                                   args, 0, stream);
    } else {
        int*          degF = (int*)ws;
        unsigned int* Sq   = (unsigned int*)(ws + (size_t)n * 4);
        float*        tF   = (float*)(ws + (size_t)n * 8);
        hipMemsetAsync(ws, 0, (size_t)n * 8 + 512, stream);
        deg_fb<<<1600, 256, 0, stream>>>(ei, degF, E);
        srcsum_fb<<<1600, 256, 0, stream>>>(ei, degF, Sq, E);
        coef_fb<<<(int)((n + 255) / 256), 256, 0, stream>>>(Sq, degF, n);
        redx_fb<<<2048, 256, 0, stream>>>(x, (const float*)Sq, tF, n);
        final_fb<<<1, FD, 0, stream>>>(W, bias, tF, out, (float)n);
    }
}

// Round 5
// 86.714 us; speedup vs baseline: 4.4875x; 4.4875x over previous
//
#include <hip/hip_runtime.h>

#define FD 128
// deg pass: packed u16 cells, 2 nodes/word, 64 KB LDS
#define CHD 32768
#define NSLD 64
// S pass: u32 cells, 64 KB LDS
#define CHS 16384
#define NSLS 64
#define RXB 512               // reduce_x blocks
#define QSCALE 16777216.0f    // 2^24
#define QINV   5.9604644775390625e-8f

__device__ __forceinline__ unsigned quant_w(int dp1) {
    return (unsigned)(rsqrtf((float)dp1) * QSCALE + 0.5f);
}

// Block-uniform dtype check: OR of first kmax odd u32 words of edge_index.
// int64 buffer => high halves all zero; int32 => random node ids, nonzero w.h.p.
__device__ __forceinline__ bool detect_is32(const unsigned int* w, unsigned int* sflag,
                                            int tid, int nthr, int kmax) {
    if (tid == 0) *sflag = 0u;
    __syncthreads();
    unsigned acc = 0;
    for (int k = tid; k < kmax; k += nthr) acc |= w[2 * k + 1];
    if (acc) atomicOr(sflag, 1u);
    __syncthreads();
    return *sflag != 0u;
}

// int64 -> int32 (no-op when already int32)
__global__ void convert_kernel(const unsigned int* __restrict__ w64,
                               int* __restrict__ e32, long long total) {
    __shared__ unsigned int sflag;
    int kmax = (int)((total / 2 < 256) ? total / 2 : 256);
    bool is32 = detect_is32(w64, &sflag, threadIdx.x, blockDim.x, kmax);
    if (is32) return;
    const long long* e64 = (const long long*)w64;
    const long long R = ((total + gridDim.x - 1) / gridDim.x + 1) & ~1LL;
    const long long base = (long long)blockIdx.x * R;
    long long end = base + R; if (end > total) end = total;
    for (long long i = base + (long long)threadIdx.x * 2; i + 1 < end;
         i += (long long)blockDim.x * 2) {
        longlong2 v = *reinterpret_cast<const longlong2*>(e64 + i);
        *reinterpret_cast<int2*>(e32 + i) = make_int2((int)v.x, (int)v.y);
    }
}

// ---- deg histogram over dst, packed u16 LDS cells ----
__global__ __launch_bounds__(512) void hist_deg_kernel(
        const void* __restrict__ ei, const int* __restrict__ e32,
        unsigned int* __restrict__ psD, long long E, long long SL, int nch) {
    __shared__ unsigned int hist[CHD / 2];
    __shared__ unsigned int sflag;
    const int tid = threadIdx.x;
    const bool is32 = detect_is32((const unsigned int*)ei, &sflag, tid, 512, 256);
    const int* DST = (is32 ? (const int*)ei : e32) + E;
    const int b = blockIdx.x;
    const int c = b % nch;
    const int j = b / nch;
    const int lo = c * CHD;
    for (int i = tid; i < CHD / 2; i += 512) hist[i] = 0u;
    __syncthreads();
    const long long e0 = (long long)j * SL;
    long long e1 = e0 + SL; if (e1 > E) e1 = E; if (e1 < e0) e1 = e0;
    const long long e1v = e0 + ((e1 - e0) & ~3LL);
    for (long long i = e0 + (long long)tid * 4; i < e1v; i += 2048) {
        int4 d = *reinterpret_cast<const int4*>(DST + i);
        unsigned u0 = (unsigned)(d.x - lo), u1 = (unsigned)(d.y - lo);
        unsigned u2 = (unsigned)(d.z - lo), u3 = (unsigned)(d.w - lo);
        if (u0 < CHD) atomicAdd(&hist[u0 >> 1], 1u << ((u0 & 1) * 16));
        if (u1 < CHD) atomicAdd(&hist[u1 >> 1], 1u << ((u1 & 1) * 16));
        if (u2 < CHD) atomicAdd(&hist[u2 >> 1], 1u << ((u2 & 1) * 16));
        if (u3 < CHD) atomicAdd(&hist[u3 >> 1], 1u << ((u3 & 1) * 16));
    }
    { long long it = e1v + tid;
      if (it < e1) { unsigned u = (unsigned)(DST[it] - lo);
                     if (u < CHD) atomicAdd(&hist[u >> 1], 1u << ((u & 1) * 16)); } }
    __syncthreads();
    unsigned int* o = psD + (size_t)b * (CHD / 2);
    for (int w = tid; w < CHD / 2; w += 512) o[w] = hist[w];
}

// ---- reduce deg partials ----
__global__ void deg_reduce_kernel(const unsigned int* __restrict__ psD,
                                  int* __restrict__ deg, long long n, int nch) {
    const long long tw = blockIdx.x * (long long)blockDim.x + threadIdx.x;
    const long long nwords = (long long)nch * (CHD / 2);
    if (tw >= nwords) return;
    const int cc = (int)(tw / (CHD / 2));
    const int w  = (int)(tw % (CHD / 2));
    unsigned s0 = 0, s1 = 0;
    for (int j = 0; j < NSLD; ++j) {
        unsigned v = psD[((size_t)j * nch + cc) * (CHD / 2) + w];
        s0 += v & 0xffffu; s1 += v >> 16;
    }
    const long long v0 = (long long)cc * CHD + 2 * w;
    if (v0 < n) deg[v0] = (int)s0;
    if (v0 + 1 < n) deg[v0 + 1] = (int)s1;
}

// ---- weighted src histogram; deg gather + quantization folded in ----
__global__ __launch_bounds__(512) void hist_s_kernel(
        const void* __restrict__ ei, const int* __restrict__ e32,
        const int* __restrict__ deg, unsigned int* __restrict__ psS,
        long long E, long long SL, int nch) {
    __shared__ unsigned int hist[CHS];
    __shared__ unsigned int sflag;
    const int tid = threadIdx.x;
    const bool is32 = detect_is32((const unsigned int*)ei, &sflag, tid, 512, 256);
    const int* SRC = is32 ? (const int*)ei : e32;
    const int* DST = SRC + E;
    const int b = blockIdx.x;
    const int c = b % nch;
    const int j = b / nch;
    const int lo = c * CHS;
    for (int i = tid; i < CHS; i += 512) hist[i] = 0u;
    __syncthreads();
    const long long e0 = (long long)j * SL;
    long long e1 = e0 + SL; if (e1 > E) e1 = E; if (e1 < e0) e1 = e0;
    const long long e1v = e0 + ((e1 - e0) & ~3LL);
    for (long long i = e0 + (long long)tid * 4; i < e1v; i += 2048) {
        int4 s = *reinterpret_cast<const int4*>(SRC + i);
        int4 d = *reinterpret_cast<const int4*>(DST + i);
        unsigned u0 = (unsigned)(s.x - lo), u1 = (unsigned)(s.y - lo);
        unsigned u2 = (unsigned)(s.z - lo), u3 = (unsigned)(s.w - lo);
        if (u0 < CHS) atomicAdd(&hist[u0], quant_w(deg[d.x] + 1));
        if (u1 < CHS) atomicAdd(&hist[u1], quant_w(deg[d.y] + 1));
        if (u2 < CHS) atomicAdd(&hist[u2], quant_w(deg[d.z] + 1));
        if (u3 < CHS) atomicAdd(&hist[u3], quant_w(deg[d.w] + 1));
    }
    { long long it = e1v + tid;
      if (it < e1) { unsigned u = (unsigned)(SRC[it] - lo);
                     if (u < CHS) atomicAdd(&hist[u], quant_w(deg[DST[it]] + 1)); } }
    __syncthreads();
    unsigned int* o = psS + (size_t)b * CHS;
    for (int w = tid; w < CHS; w += 512) o[w] = hist[w];
}

// ---- reduce S partials -> coef[v] = dinv[v]*S[v] + 1/deg[v] ----
__global__ void coef_reduce_kernel(const unsigned int* __restrict__ psS,
                                   const int* __restrict__ deg,
                                   float* __restrict__ coef, long long n, int nch) {
    const long long v = blockIdx.x * (long long)blockDim.x + threadIdx.x;
    if (v >= n) return;
    const int cc = (int)(v / CHS);
    const int u  = (int)(v % CHS);
    unsigned s = 0;
    for (int jj = 0; jj < NSLS; ++jj)
        s += psS[((size_t)jj * nch + cc) * CHS + u];
    const float dg = (float)(deg[v] + 1);
    const float di = rsqrtf(dg);
    coef[v] = di * ((float)s * QINV) + 1.0f / dg;
}

// ---- t-partials: P[b][k] = deterministic block-partial of sum_v coef[v]*x[v][k] ----
__global__ __launch_bounds__(256) void reduce_x_kernel(
        const float* __restrict__ x, const float* __restrict__ coef,
        float* __restrict__ P, long long n) {
    __shared__ float4 sm4[256];
    const int tid = threadIdx.x;
    float4 a = make_float4(0.f, 0.f, 0.f, 0.f);
    const long long tot = n * (FD / 4);
    for (long long i = blockIdx.x * 256LL + tid; i < tot; i += (long long)RXB * 256) {
        float cf = coef[i >> 5];
        float4 xv = reinterpret_cast<const float4*>(x)[i];
        a.x += cf * xv.x; a.y += cf * xv.y; a.z += cf * xv.z; a.w += cf * xv.w;
    }
    const int lane = tid & 31, grp = tid >> 5;   // 8 groups of 32
    sm4[grp * 32 + lane] = a;
    __syncthreads();
    for (int s2 = 4; s2 > 0; s2 >>= 1) {
        if (grp < s2) {
            float4 o = sm4[(grp + s2) * 32 + lane];
            float4 m = sm4[grp * 32 + lane];
            m.x += o.x; m.y += o.y; m.z += o.z; m.w += o.w;
            sm4[grp * 32 + lane] = m;
        }
        __syncthreads();
    }
    if (tid < 32) reinterpret_cast<float4*>(P)[blockIdx.x * 32 + tid] = sm4[tid];
}

// ---- fused colsum + W-matvec: out[f] = sum_j sum_k W[f,k]*P[j,k] + n*bias[f] ----
__global__ __launch_bounds__(256) void colsum_final_kernel(
        const float* __restrict__ P, const float* __restrict__ Wm,
        const float* __restrict__ bias, float* __restrict__ out, float nn) {
    __shared__ float wrow[FD];
    __shared__ float red[256];
    const int f = blockIdx.x, tid = threadIdx.x;
    if (tid < FD) wrow[tid] = Wm[f * FD + tid];
    __syncthreads();
    float part = 0.f;
    for (int j = tid; j < RXB; j += 256) {
        const float4* Pj = reinterpret_cast<const float4*>(P + (size_t)j * FD);
        #pragma unroll
        for (int k = 0; k < FD / 4; ++k) {
            float4 p = Pj[k];
            part += wrow[4 * k] * p.x + wrow[4 * k + 1] * p.y +
                    wrow[4 * k + 2] * p.z + wrow[4 * k + 3] * p.w;
        }
    }
    red[tid] = part;
    __syncthreads();
    for (int s2 = 128; s2 > 0; s2 >>= 1) {
        if (tid < s2) red[tid] += red[tid + s2];
        __syncthreads();
    }
    if (tid == 0) out[f] = red[0] + nn * bias[f];
}

// ================= fallback (R2-proven global-atomic path) =================
__global__ void deg_fb(const void* __restrict__ ei, int* __restrict__ deg, long long E) {
    __shared__ unsigned int sflag;
    int kmax = (int)((E < 256) ? (E > 1 ? E - 1 : 1) : 256);
    bool is32 = detect_is32((const unsigned int*)ei, &sflag, threadIdx.x, blockDim.x, kmax);
    const long long st = (long long)gridDim.x * blockDim.x;
    long long i = blockIdx.x * (long long)blockDim.x + threadIdx.x;
    if (is32) { const int* D = (const int*)ei + E;
        for (; i < E; i += st) atomicAdd(&deg[D[i]], 1);
    } else { const long long* D = (const long long*)ei + E;
        for (; i < E; i += st) atomicAdd(&deg[(int)D[i]], 1);
    }
}

__global__ void srcsum_fb(const void* __restrict__ ei, const int* __restrict__ deg,
                          unsigned int* __restrict__ Sq, long long E) {
    __shared__ unsigned int sflag;
    int kmax = (int)((E < 256) ? (E > 1 ? E - 1 : 1) : 256);
    bool is32 = detect_is32((const unsigned int*)ei, &sflag, threadIdx.x, blockDim.x, kmax);
    const long long st = (long long)gridDim.x * blockDim.x;
    long long i = blockIdx.x * (long long)blockDim.x + threadIdx.x;
    if (is32) { const int* S = (const int*)ei; const int* D = S + E;
        for (; i < E; i += st) atomicAdd(&Sq[S[i]], quant_w(deg[D[i]] + 1));
    } else { const long long* S = (const long long*)ei; const long long* D = S + E;
        for (; i < E; i += st) atomicAdd(&Sq[(int)S[i]], quant_w(deg[(int)D[i]] + 1));
    }
}

__global__ void coef_fb(unsigned int* __restrict__ Sq, const int* __restrict__ deg,
                        long long n) {
    const long long v = blockIdx.x * (long long)blockDim.x + threadIdx.x;
    if (v >= n) return;
    unsigned s = Sq[v];
    float dg = (float)(deg[v] + 1);
    float di = rsqrtf(dg);
    ((float*)Sq)[v] = di * ((float)s * QINV) + 1.0f / dg;
}

__global__ void redx_fb(const float* __restrict__ x, const float* __restrict__ coef,
                        float* __restrict__ t, long long n) {
    __shared__ float sm[FD];
    for (int f = threadIdx.x; f < FD; f += blockDim.x) sm[f] = 0.f;
    __syncthreads();
    const long long tot = n * (FD / 4);
    const long long st = (long long)gridDim.x * blockDim.x;
    const int lane = threadIdx.x & 31;
    float4 a = make_float4(0.f, 0.f, 0.f, 0.f);
    for (long long i = blockIdx.x * (long long)blockDim.x + threadIdx.x; i < tot; i += st) {
        float cf = coef[i >> 5];
        float4 xv = reinterpret_cast<const float4*>(x)[i];
        a.x += cf * xv.x; a.y += cf * xv.y; a.z += cf * xv.z; a.w += cf * xv.w;
    }
    atomicAdd(&sm[lane * 4 + 0], a.x);
    atomicAdd(&sm[lane * 4 + 1], a.y);
    atomicAdd(&sm[lane * 4 + 2], a.z);
    atomicAdd(&sm[lane * 4 + 3], a.w);
    __syncthreads();
    for (int f = threadIdx.x; f < FD; f += blockDim.x) atomicAdd(&t[f], sm[f]);
}

__global__ void final_fb(const float* __restrict__ Wm, const float* __restrict__ bias,
                         const float* __restrict__ t, float* __restrict__ out, float nn) {
    __shared__ float ts[FD];
    int f = threadIdx.x;
    if (f < FD) ts[f] = t[f];
    __syncthreads();
    if (f < FD) {
        float a0 = 0.f;
        #pragma unroll 16
        for (int k = 0; k < FD; ++k) a0 += Wm[f * FD + k] * ts[k];
        out[f] = a0 + nn * bias[f];
    }
}

// ==============================================================================
extern "C" void kernel_launch(void* const* d_in, const int* in_sizes, int n_in,
                              void* d_out, int out_size, void* d_ws, size_t ws_size,
                              hipStream_t stream) {
    const float* x    = (const float*)d_in[0];
    const float* W    = (const float*)d_in[1];
    const float* bias = (const float*)d_in[2];
    const void*  ei   = d_in[3];
    float* out = (float*)d_out;
    const long long n = in_sizes[0] / FD;            // 100000
    const long long E = (long long)in_sizes[3] / 2;  // 1600000

    const int NCHD = (int)((n + CHD - 1) / CHD);     // 4
    const int NCHS = (int)((n + CHS - 1) / CHS);     // 7
    const long long SLD = ((E + NSLD - 1) / NSLD + 3) & ~3LL;
    const long long SLS = ((E + NSLS - 1) / NSLS + 3) & ~3LL;
    // per-block deg cell must fit u16
    const bool u16_ok = (SLD < 65536);

    char* ws = (char*)d_ws;
    size_t off = 0;
    auto take = [&](size_t bytes) { size_t r = off; off += (bytes + 255) & ~(size_t)255; return r; };
    int*          e32  = (int*)(ws + take((size_t)2 * E * 4));
    unsigned int* psD  = (unsigned int*)(ws + take((size_t)NCHD * NSLD * (CHD / 2) * 4));
    unsigned int* psS  = (unsigned int*)(ws + take((size_t)NCHS * NSLS * CHS * 4));
    int*          deg  = (int*)(ws + take((size_t)n * 4));
    float*        coef = (float*)(ws + take((size_t)n * 4));
    float*        P    = (float*)(ws + take((size_t)RXB * FD * 4));
    const size_t need = off;

    const bool main_ok = (ws_size >= need) && ((E & 3) == 0) && (E >= 512) && u16_ok;

    if (main_ok) {
        convert_kernel<<<512, 256, 0, stream>>>((const unsigned int*)ei, e32, 2 * E);
        hist_deg_kernel<<<NCHD * NSLD, 512, 0, stream>>>(ei, e32, psD, E, SLD, NCHD);
        {
            long long nw = (long long)NCHD * (CHD / 2);
            deg_reduce_kernel<<<(int)((nw + 255) / 256), 256, 0, stream>>>(psD, deg, n, NCHD);
        }
        hist_s_kernel<<<NCHS * NSLS, 512, 0, stream>>>(ei, e32, deg, psS, E, SLS, NCHS);
        coef_reduce_kernel<<<(int)((n + 255) / 256), 256, 0, stream>>>(psS, deg, coef, n, NCHS);
        reduce_x_kernel<<<RXB, 256, 0, stream>>>(x, coef, P, n);
        colsum_final_kernel<<<FD, 256, 0, stream>>>(P, W, bias, out, (float)n);
    } else {
        int*          degF = (int*)ws;
        unsigned int* Sq   = (unsigned int*)(ws + (size_t)n * 4);
        float*        tF   = (float*)(ws + (size_t)n * 8);
        hipMemsetAsync(ws, 0, (size_t)n * 8 + 512, stream);
        deg_fb<<<1600, 256, 0, stream>>>(ei, degF, E);
        srcsum_fb<<<1600, 256, 0, stream>>>(ei, degF, Sq, E);
        coef_fb<<<(int)((n + 255) / 256), 256, 0, stream>>>(Sq, degF, n);
        redx_fb<<<2048, 256, 0, stream>>>(x, (const float*)Sq, tF, n);
        final_fb<<<1, FD, 0, stream>>>(W, bias, tF, out, (float)n);
    }
}